// Round 11
// baseline (775.201 us; speedup 1.0000x reference)
//
#include <hip/hip_runtime.h>

// ---------------- types / helpers ----------------
typedef short bh8 __attribute__((ext_vector_type(8)));     // 8 x bf16 raw
typedef float f32x4 __attribute__((ext_vector_type(4)));

#define DEVI __device__ __forceinline__

union U8 { bh8 v; unsigned short u[8]; };

DEVI float bf2f(unsigned short u){
  unsigned int x = ((unsigned int)u) << 16;
  return __builtin_bit_cast(float, x);
}
DEVI unsigned short f2bf(float f){
  unsigned int u = __builtin_bit_cast(unsigned int, f);
  u += 0x7fffu + ((u >> 16) & 1u);
  return (unsigned short)(u >> 16);
}
DEVI float sigm(float x){ return 1.0f/(1.0f + __expf(-x)); }

DEVI f32x4 MFMA(bh8 a, bh8 b, f32x4 c){
  return __builtin_amdgcn_mfma_f32_16x16x32_bf16(a, b, c, 0, 0, 0);
}

// L2-scope (sc0: L1-bypass, XCD-L2 hit) raw accessors
DEVI unsigned int ld_sc0(const unsigned int* p){
  unsigned int v;
  asm volatile("global_load_dword %0, %1, off sc0\n\ts_waitcnt vmcnt(0)"
               : "=v"(v) : "v"(p) : "memory");
  return v;
}
DEVI void st_sc0(unsigned int* p, unsigned int v){
  asm volatile("global_store_dword %0, %1, off sc0" :: "v"(p), "v"(v) : "memory");
}

// dual-path poll: bounded L2-fast probes, then agent-scope fallback.
// Correct for ANY workgroup->XCD mapping; fast when reader+writer share an L2.
DEVI float poll2(const unsigned int* fastp, const unsigned int* slowp){
  unsigned int v;
#pragma unroll 1
  for (int i = 0; i < 8; ++i){
    v = ld_sc0(fastp);
    if (v != 0xFFFFFFFFu) return __builtin_bit_cast(float, v);
  }
  int it = 0;
  do { v = __hip_atomic_load(slowp, __ATOMIC_RELAXED, __HIP_MEMORY_SCOPE_AGENT); }
  while (v == 0xFFFFFFFFu && ++it < (1 << 24));
  return __builtin_bit_cast(float, v);
}

// ---------------- fused prep device bodies ----------------
DEVI void conv_dev(const float* src, unsigned short* dst, int rows, int rstride,
                   int lblk, int nblk){
  int tid = threadIdx.x;
  size_t n = (size_t)rows * 128;      // pairs
  for (size_t i = (size_t)lblk * 256 + tid; i < n; i += (size_t)nblk * 256){
    size_t r = i >> 7; int c = ((int)(i & 127)) * 2;
    const float* s = src + r * (size_t)rstride + c;
    unsigned int hp = (unsigned int)f2bf(s[0]) | ((unsigned int)f2bf(s[1]) << 16);
    *(unsigned int*)(dst + r * 256 + c) = hp;
  }
}

DEVI void fold_dev(const float* A, int offA, int sAm, int sAk,
                   const float* Bm, int offB, int sBn, int sBk,
                   const float* addM, float* Cf, unsigned short* Cb,
                   int M, int N, int lblk, int nblk){
  int tid = threadIdx.x;
  for (int i = lblk * 256 + tid; i < M * N; i += nblk * 256){
    int m = i / N, n = i - m * N;
    const float* a = A + offA + (size_t)m * sAm;
    const float* b = Bm + offB + (size_t)n * sBn;
    float acc = 0.f;
    for (int k = 0; k < 256; ++k) acc += a[(size_t)k * sAk] * b[(size_t)k * sBk];
    if (addM) acc += addM[m];
    if (Cf) Cf[i] = acc;
    if (Cb) Cb[i] = f2bf(acc);
  }
}

// ---------------- prep mega-kernel A ----------------
__global__ __launch_bounds__(256) void k_prepA(const int* input_seq, const int* target_seq,
      const float* enc_emb, const float* dec_emb,
      const float* enc_Wih, const float* dec_Wih, const float* Wout,
      const float* enc_Whh, const float* dec_Whh,
      const float* Wq, const float* Wk, const float* bq, const float* bk,
      const float* Wo, const float* bo, const float* dec_b,
      unsigned short* src_bf, unsigned short* tok_bf,
      unsigned short* wih_bf, unsigned short* wxd_bf, unsigned short* wout_bf,
      unsigned short* whhE_bf, unsigned short* whhD_bf,
      float* Gf, unsigned short* A3bf, float* c3f, float* c4f, float* c5f, float* xdb){
  int blk = blockIdx.x, tid = threadIdx.x;
  if (blk < 512){
    for (int r = 0; r < 4; ++r){
      int m = blk * 4 + r;
      int idx = input_seq[m];
      src_bf[(size_t)m * 256 + tid] = f2bf(enc_emb[(size_t)idx * 256 + tid]);
    }
  } else if (blk < 768){
    int lb = blk - 512;
    for (int r = 0; r < 4; ++r){
      int m = lb * 4 + r;
      if (m < 1008){
        int bb = m / 63, t = m - bb * 63;
        int idx = target_seq[bb * 64 + t];
        tok_bf[(size_t)m * 256 + tid] = f2bf(dec_emb[(size_t)idx * 256 + tid]);
      } else tok_bf[(size_t)m * 256 + tid] = 0;
    }
  }
  else if (blk < 896)  conv_dev(enc_Wih, wih_bf, 1024, 256, blk - 768, 128);
  else if (blk < 1024) conv_dev(dec_Wih, wxd_bf, 1024, 512, blk - 896, 128);
  else if (blk < 2048) conv_dev(Wout,    wout_bf, 32000, 256, blk - 1024, 1024);
  else if (blk < 2176) conv_dev(enc_Whh, whhE_bf, 1024, 256, blk - 2048, 128);
  else if (blk < 2304) conv_dev(dec_Whh, whhD_bf, 1024, 256, blk - 2176, 128);
  else if (blk < 3328) fold_dev(dec_Wih,256,512,1, Wo,0,1,256, nullptr, Gf,nullptr, 1024,256, blk - 2304, 1024);
  else if (blk < 3584) fold_dev(Wq,0,1,256,        Wk,0,1,256, nullptr, nullptr,A3bf, 256,256, blk - 3328, 256);
  else if (blk == 3584) fold_dev(bk,0,0,1, Wq,0,1,256, nullptr, c3f,nullptr, 1,256, 0, 1);
  else if (blk == 3585) fold_dev(bq,0,0,1, Wk,0,1,256, nullptr, c4f,nullptr, 1,256, 0, 1);
  else if (blk == 3586) fold_dev(bq,0,0,1, bk,0,0,1,   nullptr, c5f,nullptr, 1,1,   0, 1);
  else                  fold_dev(dec_Wih,256,512,1, bo,0,0,1, dec_b, xdb,nullptr, 1024,1, blk - 3587, 4);
}

// ---------------- prep mega-kernel B ----------------
__global__ __launch_bounds__(256) void k_prepB(const float* Gf, const float* Wv,
      const float* bv, unsigned short* A2bf, float* xdb){
  int blk = blockIdx.x;
  if (blk < 512) fold_dev(Gf,0,256,1, Wv,0,1,256, nullptr, nullptr,A2bf, 1024,256, blk, 512);
  else           fold_dev(Gf,0,256,1, bv,0,0,1,   xdb,     xdb,nullptr, 1024,1,   blk - 512, 4);
}

// ---------------- bf16 MFMA GEMM tile (validated body) ----------------
DEVI void gemm_tile(const unsigned short* __restrict__ A,
      const unsigned short* __restrict__ Bw, const float* __restrict__ bias,
      float* __restrict__ Cf, unsigned short* __restrict__ Cb, int Mlog, int N,
      int tmi, int tni, unsigned short* lA, unsigned short* lB){
  int tid = threadIdx.x;
  int lane = tid & 63, wave = tid >> 6;
  int wm = wave >> 1, wn = wave & 1;
  int kg = lane >> 4, l15 = lane & 15;
  size_t tm = tmi, tn = tni;
  f32x4 acc[4][4];
#pragma unroll
  for (int i = 0; i < 4; ++i)
#pragma unroll
    for (int j = 0; j < 4; ++j) acc[i][j] = (f32x4){0.f, 0.f, 0.f, 0.f};

  for (int ks = 0; ks < 8; ++ks){
    __syncthreads();
#pragma unroll
    for (int i = 0; i < 2; ++i){
      int slot = i * 256 + tid;
      int r = slot >> 2, sg = slot & 3;
      bh8 va = *reinterpret_cast<const bh8*>(A + (tm * 128 + r) * 256 + ks * 32 + sg * 8);
      *reinterpret_cast<bh8*>((char*)lA + r * 64 + ((sg ^ (r & 3)) << 4)) = va;
      bh8 vb = *reinterpret_cast<const bh8*>(Bw + (tn * 128 + r) * 256 + ks * 32 + sg * 8);
      *reinterpret_cast<bh8*>((char*)lB + r * 64 + ((sg ^ (r & 3)) << 4)) = vb;
    }
    __syncthreads();
    bh8 af[4], bfr[4];
#pragma unroll
    for (int mi = 0; mi < 4; ++mi){
      int r = wm * 64 + mi * 16 + l15;
      af[mi] = *reinterpret_cast<const bh8*>((char*)lA + r * 64 + ((kg ^ (r & 3)) << 4));
    }
#pragma unroll
    for (int ni = 0; ni < 4; ++ni){
      int r = wn * 64 + ni * 16 + l15;
      bfr[ni] = *reinterpret_cast<const bh8*>((char*)lB + r * 64 + ((kg ^ (r & 3)) << 4));
    }
#pragma unroll
    for (int mi = 0; mi < 4; ++mi)
#pragma unroll
      for (int ni = 0; ni < 4; ++ni)
        acc[mi][ni] = MFMA(af[mi], bfr[ni], acc[mi][ni]);
  }
#pragma unroll
  for (int ni = 0; ni < 4; ++ni){
    int col = (int)tn * 128 + wn * 64 + ni * 16 + l15;
    float bv = bias ? bias[col] : 0.f;
#pragma unroll
    for (int mi = 0; mi < 4; ++mi){
#pragma unroll
      for (int rg = 0; rg < 4; ++rg){
        int row = (int)tm * 128 + wm * 64 + mi * 16 + kg * 4 + rg;
        if (row < Mlog){
          float v = acc[mi][ni][rg] + bv;
          if (Cb) Cb[(size_t)row * N + col] = f2bf(v);
          else    Cf[(size_t)row * N + col] = v;
        }
      }
    }
  }
}

// standalone GEMM (logits)
__global__ __launch_bounds__(256) void k_gemm(const unsigned short* __restrict__ A,
      const unsigned short* __restrict__ Bw, const float* __restrict__ bias,
      float* __restrict__ Cf, unsigned short* __restrict__ Cb, int Mlog, int N){
  __shared__ __align__(16) unsigned short lA[128 * 32];
  __shared__ __align__(16) unsigned short lB[128 * 32];
  gemm_tile(A, Bw, bias, Cf, Cb, Mlog, N, blockIdx.y, blockIdx.x, lA, lB);
}

// fused Xg + Xd GEMMs
__global__ __launch_bounds__(256) void k_gemmAB(const unsigned short* src_bf,
      const unsigned short* wih_bf, const float* enc_b, float* Xg,
      const unsigned short* tok_bf, const unsigned short* wxd_bf, const float* xdb, float* Xd){
  __shared__ __align__(16) unsigned short lA[128 * 32];
  __shared__ __align__(16) unsigned short lB[128 * 32];
  int blk = blockIdx.x;
  if (blk < 128) gemm_tile(src_bf, wih_bf, enc_b, Xg, nullptr, 2048, 1024, blk >> 3, blk & 7, lA, lB);
  else { int l = blk - 128; gemm_tile(tok_bf, wxd_bf, xdb, Xd, nullptr, 1024, 1024, l >> 3, l & 7, lA, lB); }
}

// fused post-encoder: KW + VWWT + sb
__global__ __launch_bounds__(256) void k_gemmPost(const unsigned short* enc_bf,
      const unsigned short* A3bf, const float* c3f, unsigned short* KWb,
      const unsigned short* A2bf, unsigned short* VWWT,
      const float* c4f, const float* c5f, float* sbf){
  __shared__ __align__(16) unsigned short lA[128 * 32];
  __shared__ __align__(16) unsigned short lB[128 * 32];
  int blk = blockIdx.x, tid = threadIdx.x;
  if (blk < 32) gemm_tile(enc_bf, A3bf, c3f, nullptr, KWb, 2048, 256, blk >> 1, blk & 1, lA, lB);
  else if (blk < 160){ int l = blk - 32; gemm_tile(A2bf, enc_bf, nullptr, nullptr, VWWT, 1024, 2048, l >> 4, l & 15, lA, lB); }
  else {
    int m = (blk - 160) * 256 + tid;
    const unsigned short* e = enc_bf + (size_t)m * 256;
    float a = 0.f;
    for (int k = 0; k < 256; ++k) a += bf2f(e[k]) * c4f[k];
    sbf[m] = a + c5f[0];
  }
}

// ---------------- grouped encoder: dual-path sentinel dataflow ----------------
__global__ __launch_bounds__(256) void k_enc_g(const unsigned short* __restrict__ Whh_bf,
      const float* __restrict__ Xg, unsigned short* __restrict__ enc_bf,
      float* hbEf, float* hbEs, float* hbDf, float* hbDs, float* cfin){
  __shared__ __align__(16) unsigned short Ws[128 * 256];  // 64 KB
  __shared__ __align__(16) float h_l[256];
  __shared__ float part[256];
  int tid = threadIdx.x, blk = blockIdx.x;
  int b = blk & 15, sub = blk >> 4, j0 = sub * 32;
  int lr = tid >> 1, kh = tid & 1;

  for (int i = 0; i < 16; ++i){
    int id = i * 256 + tid;
    int slr = id >> 5, c = id & 31;
    int R = (slr >> 5) * 256 + j0 + (slr & 31);
    bh8 v = *reinterpret_cast<const bh8*>(Whh_bf + (size_t)R * 256 + c * 8);
    *reinterpret_cast<bh8*>((char*)Ws + slr * 512 + ((c ^ (slr & 31)) << 4)) = v;
  }
  h_l[tid] = 0.f;
  float creg = 0.f;
  int Rr = (lr >> 5) * 256 + j0 + (lr & 31);
  __syncthreads();

  for (int t = 0; t < 128; ++t){
    float xg = (kh == 0) ? Xg[(size_t)(b * 128 + t) * 1024 + Rr] : 0.f;  // overlaps poll
    if (t > 0 && (tid >> 5) != sub)
      h_l[tid] = poll2((const unsigned int*)hbEf + (size_t)t * 4096 + b * 256 + tid,
                       (const unsigned int*)hbEs + (size_t)t * 4096 + b * 256 + tid);
    __syncthreads();
    {
      float acc = xg;
#pragma unroll
      for (int ci = 0; ci < 16; ++ci){
        int chunk = kh * 16 + ci;
        U8 w; w.v = *reinterpret_cast<const bh8*>((char*)Ws + lr * 512 + ((chunk ^ (lr & 31)) << 4));
        float4 ha = *(const float4*)(h_l + chunk * 8);
        float4 hb = *(const float4*)(h_l + chunk * 8 + 4);
        acc += ha.x*bf2f(w.u[0]) + ha.y*bf2f(w.u[1]) + ha.z*bf2f(w.u[2]) + ha.w*bf2f(w.u[3]);
        acc += hb.x*bf2f(w.u[4]) + hb.y*bf2f(w.u[5]) + hb.z*bf2f(w.u[6]) + hb.w*bf2f(w.u[7]);
      }
      part[tid] = acc;
    }
    __syncthreads();
    if (tid < 32){
      float gi = part[tid*2]      + part[tid*2 + 1];
      float gf = part[(32+tid)*2] + part[(32+tid)*2 + 1];
      float gg = part[(64+tid)*2] + part[(64+tid)*2 + 1];
      float go = part[(96+tid)*2] + part[(96+tid)*2 + 1];
      float c = sigm(gf) * creg + sigm(gi) * tanhf(gg);
      float h = sigm(go) * tanhf(c);
      creg = c;
      int j = j0 + tid;
      h_l[j] = h;
      unsigned int hb = __builtin_bit_cast(unsigned int, h);
      if (t < 127){
        st_sc0((unsigned int*)hbEf + (size_t)(t + 1) * 4096 + b * 256 + j, hb);
        __hip_atomic_store((unsigned int*)hbEs + (size_t)(t + 1) * 4096 + b * 256 + j, hb,
                           __ATOMIC_RELAXED, __HIP_MEMORY_SCOPE_AGENT);
      } else {
        hbDf[b * 256 + j] = h;          // cross-kernel: flushed at kernel end
        hbDs[b * 256 + j] = h;
        cfin[b * 256 + j] = c;
      }
      enc_bf[(size_t)(b * 128 + t) * 256 + j] = f2bf(h);
    }
  }
}

// ---------------- one-hop decoder: dual-path sentinel dataflow ----------------
__global__ __launch_bounds__(256) void k_dec_g(const unsigned short* __restrict__ Whh_bf,
      const float* __restrict__ Xd, const unsigned short* __restrict__ KW,
      const unsigned short* __restrict__ VWWT, const float* __restrict__ sb,
      float* hbDf, float* hbDs, const float* __restrict__ cfin,
      unsigned short* __restrict__ Hs){
  __shared__ __align__(16) unsigned short KW_l[128 * 256];  // 64 KB
  __shared__ __align__(16) unsigned short Ws[128 * 256];    // 64 KB
  __shared__ __align__(16) float h_l[256];
  __shared__ float part[256];
  __shared__ float sc_l[128];
  __shared__ float at_l[128];
  __shared__ float red0, red1;
  int tid = threadIdx.x, blk = blockIdx.x;
  int b = blk & 15, sub = blk >> 4, j0 = sub * 32;
  int ss = tid >> 1, kh = tid & 1;
  int lr = ss;

  for (int i = 0; i < 16; ++i){
    int id = i * 256 + tid;
    int row = id >> 5, c = id & 31;
    bh8 v = *reinterpret_cast<const bh8*>(KW + (size_t)(b * 128 + row) * 256 + c * 8);
    *reinterpret_cast<bh8*>((char*)KW_l + row * 512 + ((c ^ (row & 31)) << 4)) = v;
  }
  for (int i = 0; i < 16; ++i){
    int id = i * 256 + tid;
    int row = id >> 5, c = id & 31;
    int R = (row >> 5) * 256 + j0 + (row & 31);
    bh8 v = *reinterpret_cast<const bh8*>(Whh_bf + (size_t)R * 256 + c * 8);
    *reinterpret_cast<bh8*>((char*)Ws + row * 512 + ((c ^ (row & 31)) << 4)) = v;
  }
  int Rr = (lr >> 5) * 256 + j0 + (lr & 31);
  U8 vw[8];
#pragma unroll
  for (int ci = 0; ci < 8; ++ci)
    vw[ci].v = *reinterpret_cast<const bh8*>(VWWT + (size_t)Rr * 2048 + b * 128 + kh * 64 + ci * 8);
  float sbreg = (tid < 128) ? sb[b * 128 + tid] : 0.f;
  float creg = (tid < 32) ? cfin[b * 256 + j0 + tid] : 0.f;
  __syncthreads();

  for (int t = 0; t < 63; ++t){
    float xdreg = (kh == 0) ? Xd[(size_t)(b * 63 + t) * 1024 + Rr] : 0.f;  // overlaps poll
    if (t == 0 || (tid >> 5) != sub)
      h_l[tid] = poll2((const unsigned int*)hbDf + (size_t)t * 4096 + b * 256 + tid,
                       (const unsigned int*)hbDs + (size_t)t * 4096 + b * 256 + tid);
    __syncthreads();
    // scores partial
    {
      float a = 0.f;
#pragma unroll
      for (int i = 0; i < 16; ++i){
        int ch = kh * 16 + i;
        U8 ku; ku.v = *reinterpret_cast<const bh8*>((char*)KW_l + ss * 512 + ((ch ^ (ss & 31)) << 4));
        const float* hp = h_l + ch * 8;
#pragma unroll
        for (int q = 0; q < 8; ++q) a += hp[q] * bf2f(ku.u[q]);
      }
      part[tid] = a;
    }
    __syncthreads();
    if (tid < 128) sc_l[tid] = (part[2 * tid] + part[2 * tid + 1] + sbreg) * 0.0625f;
    __syncthreads();
    if (tid < 64){
      float m = fmaxf(sc_l[tid], sc_l[tid + 64]);
      for (int o = 32; o; o >>= 1) m = fmaxf(m, __shfl_xor(m, o));
      if (tid == 0) red0 = m;
    }
    __syncthreads();
    if (tid < 128) sc_l[tid] = __expf(sc_l[tid] - red0);
    __syncthreads();
    if (tid < 64){
      float s = sc_l[tid] + sc_l[tid + 64];
      for (int o = 32; o; o >>= 1) s += __shfl_xor(s, o);
      if (tid == 0) red1 = s;
    }
    __syncthreads();
    if (tid < 128) at_l[tid] = sc_l[tid] / red1;
    __syncthreads();
    // gates partial
    {
      float acc = xdreg;
#pragma unroll
      for (int ci = 0; ci < 16; ++ci){
        int ch = kh * 16 + ci;
        U8 w; w.v = *reinterpret_cast<const bh8*>((char*)Ws + lr * 512 + ((ch ^ (lr & 31)) << 4));
        float4 ha = *(const float4*)(h_l + ch * 8);
        float4 hb = *(const float4*)(h_l + ch * 8 + 4);
        acc += ha.x*bf2f(w.u[0]) + ha.y*bf2f(w.u[1]) + ha.z*bf2f(w.u[2]) + ha.w*bf2f(w.u[3]);
        acc += hb.x*bf2f(w.u[4]) + hb.y*bf2f(w.u[5]) + hb.z*bf2f(w.u[6]) + hb.w*bf2f(w.u[7]);
      }
#pragma unroll
      for (int ci = 0; ci < 8; ++ci){
        const float* ap = at_l + kh * 64 + ci * 8;
#pragma unroll
        for (int q = 0; q < 8; ++q) acc += ap[q] * bf2f(vw[ci].u[q]);
      }
      part[tid] = acc;
    }
    __syncthreads();
    if (tid < 32){
      float gi = part[tid*2]      + part[tid*2 + 1];
      float gf = part[(32+tid)*2] + part[(32+tid)*2 + 1];
      float gg = part[(64+tid)*2] + part[(64+tid)*2 + 1];
      float go = part[(96+tid)*2] + part[(96+tid)*2 + 1];
      float c = sigm(gf) * creg + sigm(gi) * tanhf(gg);
      float h = sigm(go) * tanhf(c);
      creg = c;
      int j = j0 + tid;
      h_l[j] = h;
      unsigned int hb = __builtin_bit_cast(unsigned int, h);
      st_sc0((unsigned int*)hbDf + (size_t)(t + 1) * 4096 + b * 256 + j, hb);
      __hip_atomic_store((unsigned int*)hbDs + (size_t)(t + 1) * 4096 + b * 256 + j, hb,
                         __ATOMIC_RELAXED, __HIP_MEMORY_SCOPE_AGENT);
      Hs[(size_t)(b * 63 + t) * 256 + j] = f2bf(h);
    }
    __syncthreads();
  }
}

// ---------------- host ----------------
extern "C" void kernel_launch(void* const* d_in, const int* in_sizes, int n_in,
                              void* d_out, int out_size, void* d_ws, size_t ws_size,
                              hipStream_t stream){
  const int expect[20] = {2048, 1024, 8192000, 262144, 262144, 1024, 8192000,
                          65536, 256, 65536, 256, 65536, 256, 65536, 256,
                          524288, 262144, 1024, 8192000, 32000};
  if (n_in != 20 || out_size != 32256000) return;
  for (int i = 0; i < 20; ++i) if (in_sizes[i] != expect[i]) return;

  const int*   input_seq  = (const int*)  d_in[0];
  const int*   target_seq = (const int*)  d_in[1];
  const float* enc_emb    = (const float*)d_in[2];
  const float* enc_Wih    = (const float*)d_in[3];
  const float* enc_Whh    = (const float*)d_in[4];
  const float* enc_b      = (const float*)d_in[5];
  const float* dec_emb    = (const float*)d_in[6];
  const float* Wq         = (const float*)d_in[7];
  const float* bq         = (const float*)d_in[8];
  const float* Wk         = (const float*)d_in[9];
  const float* bk         = (const float*)d_in[10];
  const float* Wv         = (const float*)d_in[11];
  const float* bv         = (const float*)d_in[12];
  const float* Wo         = (const float*)d_in[13];
  const float* bo         = (const float*)d_in[14];
  const float* dec_Wih    = (const float*)d_in[15];
  const float* dec_Whh    = (const float*)d_in[16];
  const float* dec_b      = (const float*)d_in[17];
  const float* Wout       = (const float*)d_in[18];
  const float* bout       = (const float*)d_in[19];

  char* p = (char*)d_ws;
  auto alloc = [&](size_t sz)->char*{ char* r = p; p += (sz + 255) & ~(size_t)255; return r; };

  // ---- zero zone ----
  unsigned short* Hs     = (unsigned short*)alloc((size_t)1024 * 256 * 2);
  size_t zsz = (size_t)(p - (char*)d_ws);
  // ---- sentinel (0xFF) zone: fast (L2) + slow (agent) mirrors, write-once ----
  float*          hbEf   = (float*)         alloc((size_t)128 * 4096 * 4);
  float*          hbEs   = (float*)         alloc((size_t)128 * 4096 * 4);
  float*          hbDf   = (float*)         alloc((size_t)64 * 4096 * 4);
  float*          hbDs   = (float*)         alloc((size_t)64 * 4096 * 4);
  size_t ffend = (size_t)(p - (char*)d_ws);
  // ---- working buffers (fully written before read) ----
  float*          cfin   = (float*)          alloc(16 * 256 * 4);
  unsigned short* src_bf  = (unsigned short*)alloc((size_t)2048 * 256 * 2);
  unsigned short* tok_bf  = (unsigned short*)alloc((size_t)1024 * 256 * 2);
  unsigned short* wih_bf  = (unsigned short*)alloc((size_t)1024 * 256 * 2);
  unsigned short* wxd_bf  = (unsigned short*)alloc((size_t)1024 * 256 * 2);
  unsigned short* wout_bf = (unsigned short*)alloc((size_t)32000 * 256 * 2);
  unsigned short* whhE_bf = (unsigned short*)alloc((size_t)1024 * 256 * 2);
  unsigned short* whhD_bf = (unsigned short*)alloc((size_t)1024 * 256 * 2);
  float*          Gf      = (float*)         alloc((size_t)1024 * 256 * 4);
  unsigned short* A3bf    = (unsigned short*)alloc((size_t)256 * 256 * 2);
  unsigned short* A2bf    = (unsigned short*)alloc((size_t)1024 * 256 * 2);
  float*          c3f     = (float*)         alloc(256 * 4);
  float*          c4f     = (float*)         alloc(256 * 4);
  float*          c5f     = (float*)         alloc(256);
  float*          xdb     = (float*)         alloc(1024 * 4);
  float*          Xg      = (float*)         alloc((size_t)2048 * 1024 * 4);
  float*          Xd      = (float*)         alloc((size_t)1024 * 1024 * 4);
  unsigned short* enc_bf  = (unsigned short*)alloc((size_t)2048 * 256 * 2);
  unsigned short* KWb     = (unsigned short*)alloc((size_t)2048 * 256 * 2);
  unsigned short* VWWT    = (unsigned short*)alloc((size_t)1024 * 2048 * 2);
  float*          sbf     = (float*)         alloc(2048 * 4);
  if ((size_t)(p - (char*)d_ws) > ws_size) return;

  hipMemsetAsync(d_ws, 0, zsz, stream);
  hipMemsetAsync((char*)d_ws + zsz, 0xFF, ffend - zsz, stream);   // sentinel fill
  hipMemsetAsync(hbEf, 0, 4096 * 4, stream);                      // h_0 = zeros (both mirrors)
  hipMemsetAsync(hbEs, 0, 4096 * 4, stream);

  // fused prep
  k_prepA<<<3591, 256, 0, stream>>>(input_seq, target_seq, enc_emb, dec_emb,
      enc_Wih, dec_Wih, Wout, enc_Whh, dec_Whh, Wq, Wk, bq, bk, Wo, bo, dec_b,
      src_bf, tok_bf, wih_bf, wxd_bf, wout_bf, whhE_bf, whhD_bf,
      Gf, A3bf, c3f, c4f, c5f, xdb);
  k_prepB<<<516, 256, 0, stream>>>(Gf, Wv, bv, A2bf, xdb);

  // fused Xg + Xd GEMMs
  k_gemmAB<<<192, 256, 0, stream>>>(src_bf, wih_bf, enc_b, Xg, tok_bf, wxd_bf, xdb, Xd);

  // encoder: dual-path sentinel dataflow
  k_enc_g<<<128, 256, 0, stream>>>(whhE_bf, Xg, enc_bf, hbEf, hbEs, hbDf, hbDs, cfin);

  // fused post-encoder: KW + VWWT + sb
  k_gemmPost<<<168, 256, 0, stream>>>(enc_bf, A3bf, c3f, KWb, A2bf, VWWT, c4f, c5f, sbf);

  // decoder: one-hop dual-path sentinel dataflow
  k_dec_g<<<128, 256, 0, stream>>>(whhD_bf, Xd, KWb, VWWT, sbf, hbDf, hbDs, cfin, Hs);

  // logits -> FP32 d_out
  k_gemm<<<dim3(250, 8), 256, 0, stream>>>(Hs, wout_bf, bout, (float*)d_out, nullptr, 1008, 32000);
}

// Round 12
// 683.968 us; speedup vs baseline: 1.1334x; 1.1334x over previous
//
#include <hip/hip_runtime.h>

// ---------------- types / helpers ----------------
typedef short bh8 __attribute__((ext_vector_type(8)));     // 8 x bf16 raw
typedef float f32x4 __attribute__((ext_vector_type(4)));

#define DEVI __device__ __forceinline__

union U8 { bh8 v; unsigned short u[8]; };

DEVI float bf2f(unsigned short u){
  unsigned int x = ((unsigned int)u) << 16;
  return __builtin_bit_cast(float, x);
}
DEVI unsigned short f2bf(float f){
  unsigned int u = __builtin_bit_cast(unsigned int, f);
  u += 0x7fffu + ((u >> 16) & 1u);
  return (unsigned short)(u >> 16);
}
DEVI float sigm(float x){ return 1.0f/(1.0f + __expf(-x)); }

DEVI f32x4 MFMA(bh8 a, bh8 b, f32x4 c){
  return __builtin_amdgcn_mfma_f32_16x16x32_bf16(a, b, c, 0, 0, 0);
}

// fast-lane accessors: PLAIN store (write-through vL1 -> writer XCD L2, dirty line);
// sc0 load (L1-bypass, L2 lookup). Same-XCD reader sees the dirty L2 line.
DEVI unsigned int ld_sc0(const unsigned int* p){
  unsigned int v;
  asm volatile("global_load_dword %0, %1, off sc0\n\ts_waitcnt vmcnt(0)"
               : "=v"(v) : "v"(p) : "memory");
  return v;
}
DEVI void st_plain(unsigned int* p, unsigned int v){
  asm volatile("global_store_dword %0, %1, off" :: "v"(p), "v"(v) : "memory");
}

// interleaved dual-path poll: alternate L2-fast probe and agent-scope probe.
// Correct for ANY workgroup->XCD mapping; fast when reader+writer share an L2.
DEVI float poll2(const unsigned int* fastp, const unsigned int* slowp){
  unsigned int v;
  for (int it = 0; it < (1 << 23); ++it){
    v = ld_sc0(fastp);
    if (v != 0xFFFFFFFFu) return __builtin_bit_cast(float, v);
    v = __hip_atomic_load(slowp, __ATOMIC_RELAXED, __HIP_MEMORY_SCOPE_AGENT);
    if (v != 0xFFFFFFFFu) return __builtin_bit_cast(float, v);
  }
  return __builtin_bit_cast(float, v);
}

// ---------------- fused prep device bodies ----------------
DEVI void conv_dev(const float* src, unsigned short* dst, int rows, int rstride,
                   int lblk, int nblk){
  int tid = threadIdx.x;
  size_t n = (size_t)rows * 128;      // pairs
  for (size_t i = (size_t)lblk * 256 + tid; i < n; i += (size_t)nblk * 256){
    size_t r = i >> 7; int c = ((int)(i & 127)) * 2;
    const float* s = src + r * (size_t)rstride + c;
    unsigned int hp = (unsigned int)f2bf(s[0]) | ((unsigned int)f2bf(s[1]) << 16);
    *(unsigned int*)(dst + r * 256 + c) = hp;
  }
}

DEVI void fold_dev(const float* A, int offA, int sAm, int sAk,
                   const float* Bm, int offB, int sBn, int sBk,
                   const float* addM, float* Cf, unsigned short* Cb,
                   int M, int N, int lblk, int nblk){
  int tid = threadIdx.x;
  for (int i = lblk * 256 + tid; i < M * N; i += nblk * 256){
    int m = i / N, n = i - m * N;
    const float* a = A + offA + (size_t)m * sAm;
    const float* b = Bm + offB + (size_t)n * sBn;
    float acc = 0.f;
    for (int k = 0; k < 256; ++k) acc += a[(size_t)k * sAk] * b[(size_t)k * sBk];
    if (addM) acc += addM[m];
    if (Cf) Cf[i] = acc;
    if (Cb) Cb[i] = f2bf(acc);
  }
}

// ---------------- prep mega-kernel A ----------------
__global__ __launch_bounds__(256) void k_prepA(const int* input_seq, const int* target_seq,
      const float* enc_emb, const float* dec_emb,
      const float* enc_Wih, const float* dec_Wih, const float* Wout,
      const float* enc_Whh, const float* dec_Whh,
      const float* Wq, const float* Wk, const float* bq, const float* bk,
      const float* Wo, const float* bo, const float* dec_b,
      unsigned short* src_bf, unsigned short* tok_bf,
      unsigned short* wih_bf, unsigned short* wxd_bf, unsigned short* wout_bf,
      unsigned short* whhE_bf, unsigned short* whhD_bf,
      float* Gf, unsigned short* A3bf, float* c3f, float* c4f, float* c5f, float* xdb){
  int blk = blockIdx.x, tid = threadIdx.x;
  if (blk < 512){
    for (int r = 0; r < 4; ++r){
      int m = blk * 4 + r;
      int idx = input_seq[m];
      src_bf[(size_t)m * 256 + tid] = f2bf(enc_emb[(size_t)idx * 256 + tid]);
    }
  } else if (blk < 768){
    int lb = blk - 512;
    for (int r = 0; r < 4; ++r){
      int m = lb * 4 + r;
      if (m < 1008){
        int bb = m / 63, t = m - bb * 63;
        int idx = target_seq[bb * 64 + t];
        tok_bf[(size_t)m * 256 + tid] = f2bf(dec_emb[(size_t)idx * 256 + tid]);
      } else tok_bf[(size_t)m * 256 + tid] = 0;
    }
  }
  else if (blk < 896)  conv_dev(enc_Wih, wih_bf, 1024, 256, blk - 768, 128);
  else if (blk < 1024) conv_dev(dec_Wih, wxd_bf, 1024, 512, blk - 896, 128);
  else if (blk < 2048) conv_dev(Wout,    wout_bf, 32000, 256, blk - 1024, 1024);
  else if (blk < 2176) conv_dev(enc_Whh, whhE_bf, 1024, 256, blk - 2048, 128);
  else if (blk < 2304) conv_dev(dec_Whh, whhD_bf, 1024, 256, blk - 2176, 128);
  else if (blk < 3328) fold_dev(dec_Wih,256,512,1, Wo,0,1,256, nullptr, Gf,nullptr, 1024,256, blk - 2304, 1024);
  else if (blk < 3584) fold_dev(Wq,0,1,256,        Wk,0,1,256, nullptr, nullptr,A3bf, 256,256, blk - 3328, 256);
  else if (blk == 3584) fold_dev(bk,0,0,1, Wq,0,1,256, nullptr, c3f,nullptr, 1,256, 0, 1);
  else if (blk == 3585) fold_dev(bq,0,0,1, Wk,0,1,256, nullptr, c4f,nullptr, 1,256, 0, 1);
  else if (blk == 3586) fold_dev(bq,0,0,1, bk,0,0,1,   nullptr, c5f,nullptr, 1,1,   0, 1);
  else                  fold_dev(dec_Wih,256,512,1, bo,0,0,1, dec_b, xdb,nullptr, 1024,1, blk - 3587, 4);
}

// ---------------- prep mega-kernel B ----------------
__global__ __launch_bounds__(256) void k_prepB(const float* Gf, const float* Wv,
      const float* bv, unsigned short* A2bf, float* xdb){
  int blk = blockIdx.x;
  if (blk < 512) fold_dev(Gf,0,256,1, Wv,0,1,256, nullptr, nullptr,A2bf, 1024,256, blk, 512);
  else           fold_dev(Gf,0,256,1, bv,0,0,1,   xdb,     xdb,nullptr, 1024,1,   blk - 512, 4);
}

// ---------------- bf16 MFMA GEMM tile (validated body) ----------------
DEVI void gemm_tile(const unsigned short* __restrict__ A,
      const unsigned short* __restrict__ Bw, const float* __restrict__ bias,
      float* __restrict__ Cf, unsigned short* __restrict__ Cb, int Mlog, int N,
      int tmi, int tni, unsigned short* lA, unsigned short* lB){
  int tid = threadIdx.x;
  int lane = tid & 63, wave = tid >> 6;
  int wm = wave >> 1, wn = wave & 1;
  int kg = lane >> 4, l15 = lane & 15;
  size_t tm = tmi, tn = tni;
  f32x4 acc[4][4];
#pragma unroll
  for (int i = 0; i < 4; ++i)
#pragma unroll
    for (int j = 0; j < 4; ++j) acc[i][j] = (f32x4){0.f, 0.f, 0.f, 0.f};

  for (int ks = 0; ks < 8; ++ks){
    __syncthreads();
#pragma unroll
    for (int i = 0; i < 2; ++i){
      int slot = i * 256 + tid;
      int r = slot >> 2, sg = slot & 3;
      bh8 va = *reinterpret_cast<const bh8*>(A + (tm * 128 + r) * 256 + ks * 32 + sg * 8);
      *reinterpret_cast<bh8*>((char*)lA + r * 64 + ((sg ^ (r & 3)) << 4)) = va;
      bh8 vb = *reinterpret_cast<const bh8*>(Bw + (tn * 128 + r) * 256 + ks * 32 + sg * 8);
      *reinterpret_cast<bh8*>((char*)lB + r * 64 + ((sg ^ (r & 3)) << 4)) = vb;
    }
    __syncthreads();
    bh8 af[4], bfr[4];
#pragma unroll
    for (int mi = 0; mi < 4; ++mi){
      int r = wm * 64 + mi * 16 + l15;
      af[mi] = *reinterpret_cast<const bh8*>((char*)lA + r * 64 + ((kg ^ (r & 3)) << 4));
    }
#pragma unroll
    for (int ni = 0; ni < 4; ++ni){
      int r = wn * 64 + ni * 16 + l15;
      bfr[ni] = *reinterpret_cast<const bh8*>((char*)lB + r * 64 + ((kg ^ (r & 3)) << 4));
    }
#pragma unroll
    for (int mi = 0; mi < 4; ++mi)
#pragma unroll
      for (int ni = 0; ni < 4; ++ni)
        acc[mi][ni] = MFMA(af[mi], bfr[ni], acc[mi][ni]);
  }
#pragma unroll
  for (int ni = 0; ni < 4; ++ni){
    int col = (int)tn * 128 + wn * 64 + ni * 16 + l15;
    float bv = bias ? bias[col] : 0.f;
#pragma unroll
    for (int mi = 0; mi < 4; ++mi){
#pragma unroll
      for (int rg = 0; rg < 4; ++rg){
        int row = (int)tm * 128 + wm * 64 + mi * 16 + kg * 4 + rg;
        if (row < Mlog){
          float v = acc[mi][ni][rg] + bv;
          if (Cb) Cb[(size_t)row * N + col] = f2bf(v);
          else    Cf[(size_t)row * N + col] = v;
        }
      }
    }
  }
}

// standalone GEMM (logits)
__global__ __launch_bounds__(256) void k_gemm(const unsigned short* __restrict__ A,
      const unsigned short* __restrict__ Bw, const float* __restrict__ bias,
      float* __restrict__ Cf, unsigned short* __restrict__ Cb, int Mlog, int N){
  __shared__ __align__(16) unsigned short lA[128 * 32];
  __shared__ __align__(16) unsigned short lB[128 * 32];
  gemm_tile(A, Bw, bias, Cf, Cb, Mlog, N, blockIdx.y, blockIdx.x, lA, lB);
}

// fused Xg + Xd GEMMs
__global__ __launch_bounds__(256) void k_gemmAB(const unsigned short* src_bf,
      const unsigned short* wih_bf, const float* enc_b, float* Xg,
      const unsigned short* tok_bf, const unsigned short* wxd_bf, const float* xdb, float* Xd){
  __shared__ __align__(16) unsigned short lA[128 * 32];
  __shared__ __align__(16) unsigned short lB[128 * 32];
  int blk = blockIdx.x;
  if (blk < 128) gemm_tile(src_bf, wih_bf, enc_b, Xg, nullptr, 2048, 1024, blk >> 3, blk & 7, lA, lB);
  else { int l = blk - 128; gemm_tile(tok_bf, wxd_bf, xdb, Xd, nullptr, 1024, 1024, l >> 3, l & 7, lA, lB); }
}

// fused post-encoder: KW + VWWT + sb
__global__ __launch_bounds__(256) void k_gemmPost(const unsigned short* enc_bf,
      const unsigned short* A3bf, const float* c3f, unsigned short* KWb,
      const unsigned short* A2bf, unsigned short* VWWT,
      const float* c4f, const float* c5f, float* sbf){
  __shared__ __align__(16) unsigned short lA[128 * 32];
  __shared__ __align__(16) unsigned short lB[128 * 32];
  int blk = blockIdx.x, tid = threadIdx.x;
  if (blk < 32) gemm_tile(enc_bf, A3bf, c3f, nullptr, KWb, 2048, 256, blk >> 1, blk & 1, lA, lB);
  else if (blk < 160){ int l = blk - 32; gemm_tile(A2bf, enc_bf, nullptr, nullptr, VWWT, 1024, 2048, l >> 4, l & 15, lA, lB); }
  else {
    int m = (blk - 160) * 256 + tid;
    const unsigned short* e = enc_bf + (size_t)m * 256;
    float a = 0.f;
    for (int k = 0; k < 256; ++k) a += bf2f(e[k]) * c4f[k];
    sbf[m] = a + c5f[0];
  }
}

// ---------------- grouped encoder: dual-path (plain-store L2 lane) ----------------
__global__ __launch_bounds__(256) void k_enc_g(const unsigned short* __restrict__ Whh_bf,
      const float* __restrict__ Xg, unsigned short* __restrict__ enc_bf,
      float* hbEf, float* hbEs, float* hbDf, float* hbDs, float* cfin){
  __shared__ __align__(16) unsigned short Ws[128 * 256];  // 64 KB
  __shared__ __align__(16) float h_l[256];
  __shared__ float part[256];
  int tid = threadIdx.x, blk = blockIdx.x;
  int b = blk & 15, sub = blk >> 4, j0 = sub * 32;
  int lr = tid >> 1, kh = tid & 1;

  for (int i = 0; i < 16; ++i){
    int id = i * 256 + tid;
    int slr = id >> 5, c = id & 31;
    int R = (slr >> 5) * 256 + j0 + (slr & 31);
    bh8 v = *reinterpret_cast<const bh8*>(Whh_bf + (size_t)R * 256 + c * 8);
    *reinterpret_cast<bh8*>((char*)Ws + slr * 512 + ((c ^ (slr & 31)) << 4)) = v;
  }
  h_l[tid] = 0.f;
  float creg = 0.f;
  int Rr = (lr >> 5) * 256 + j0 + (lr & 31);
  __syncthreads();

  for (int t = 0; t < 128; ++t){
    float xg = (kh == 0) ? Xg[(size_t)(b * 128 + t) * 1024 + Rr] : 0.f;  // overlaps poll
    if (t > 0 && (tid >> 5) != sub)
      h_l[tid] = poll2((const unsigned int*)hbEf + (size_t)t * 4096 + b * 256 + tid,
                       (const unsigned int*)hbEs + (size_t)t * 4096 + b * 256 + tid);
    __syncthreads();
    {
      float acc = xg;
#pragma unroll
      for (int ci = 0; ci < 16; ++ci){
        int chunk = kh * 16 + ci;
        U8 w; w.v = *reinterpret_cast<const bh8*>((char*)Ws + lr * 512 + ((chunk ^ (lr & 31)) << 4));
        float4 ha = *(const float4*)(h_l + chunk * 8);
        float4 hb = *(const float4*)(h_l + chunk * 8 + 4);
        acc += ha.x*bf2f(w.u[0]) + ha.y*bf2f(w.u[1]) + ha.z*bf2f(w.u[2]) + ha.w*bf2f(w.u[3]);
        acc += hb.x*bf2f(w.u[4]) + hb.y*bf2f(w.u[5]) + hb.z*bf2f(w.u[6]) + hb.w*bf2f(w.u[7]);
      }
      part[tid] = acc;
    }
    __syncthreads();
    if (tid < 32){
      float gi = part[tid*2]      + part[tid*2 + 1];
      float gf = part[(32+tid)*2] + part[(32+tid)*2 + 1];
      float gg = part[(64+tid)*2] + part[(64+tid)*2 + 1];
      float go = part[(96+tid)*2] + part[(96+tid)*2 + 1];
      float c = sigm(gf) * creg + sigm(gi) * tanhf(gg);
      float h = sigm(go) * tanhf(c);
      creg = c;
      int j = j0 + tid;
      h_l[j] = h;
      unsigned int hb = __builtin_bit_cast(unsigned int, h);
      if (t < 127){
        st_plain((unsigned int*)hbEf + (size_t)(t + 1) * 4096 + b * 256 + j, hb);
        __hip_atomic_store((unsigned int*)hbEs + (size_t)(t + 1) * 4096 + b * 256 + j, hb,
                           __ATOMIC_RELAXED, __HIP_MEMORY_SCOPE_AGENT);
      } else {
        hbDf[b * 256 + j] = h;          // cross-kernel: flushed at kernel end
        hbDs[b * 256 + j] = h;
        cfin[b * 256 + j] = c;
      }
      enc_bf[(size_t)(b * 128 + t) * 256 + j] = f2bf(h);
    }
  }
}

// ---------------- one-hop decoder: dual-path (plain-store L2 lane) ----------------
__global__ __launch_bounds__(256) void k_dec_g(const unsigned short* __restrict__ Whh_bf,
      const float* __restrict__ Xd, const unsigned short* __restrict__ KW,
      const unsigned short* __restrict__ VWWT, const float* __restrict__ sb,
      float* hbDf, float* hbDs, const float* __restrict__ cfin,
      unsigned short* __restrict__ Hs){
  __shared__ __align__(16) unsigned short KW_l[128 * 256];  // 64 KB
  __shared__ __align__(16) unsigned short Ws[128 * 256];    // 64 KB
  __shared__ __align__(16) float h_l[256];
  __shared__ float part[256];
  __shared__ float sc_l[128];
  __shared__ float at_l[128];
  __shared__ float red0, red1;
  int tid = threadIdx.x, blk = blockIdx.x;
  int b = blk & 15, sub = blk >> 4, j0 = sub * 32;
  int ss = tid >> 1, kh = tid & 1;
  int lr = ss;

  for (int i = 0; i < 16; ++i){
    int id = i * 256 + tid;
    int row = id >> 5, c = id & 31;
    bh8 v = *reinterpret_cast<const bh8*>(KW + (size_t)(b * 128 + row) * 256 + c * 8);
    *reinterpret_cast<bh8*>((char*)KW_l + row * 512 + ((c ^ (row & 31)) << 4)) = v;
  }
  for (int i = 0; i < 16; ++i){
    int id = i * 256 + tid;
    int row = id >> 5, c = id & 31;
    int R = (row >> 5) * 256 + j0 + (row & 31);
    bh8 v = *reinterpret_cast<const bh8*>(Whh_bf + (size_t)R * 256 + c * 8);
    *reinterpret_cast<bh8*>((char*)Ws + row * 512 + ((c ^ (row & 31)) << 4)) = v;
  }
  int Rr = (lr >> 5) * 256 + j0 + (lr & 31);
  U8 vw[8];
#pragma unroll
  for (int ci = 0; ci < 8; ++ci)
    vw[ci].v = *reinterpret_cast<const bh8*>(VWWT + (size_t)Rr * 2048 + b * 128 + kh * 64 + ci * 8);
  float sbreg = (tid < 128) ? sb[b * 128 + tid] : 0.f;
  float creg = (tid < 32) ? cfin[b * 256 + j0 + tid] : 0.f;
  __syncthreads();

  for (int t = 0; t < 63; ++t){
    float xdreg = (kh == 0) ? Xd[(size_t)(b * 63 + t) * 1024 + Rr] : 0.f;  // overlaps poll
    if (t == 0 || (tid >> 5) != sub)
      h_l[tid] = poll2((const unsigned int*)hbDf + (size_t)t * 4096 + b * 256 + tid,
                       (const unsigned int*)hbDs + (size_t)t * 4096 + b * 256 + tid);
    __syncthreads();
    // scores partial
    {
      float a = 0.f;
#pragma unroll
      for (int i = 0; i < 16; ++i){
        int ch = kh * 16 + i;
        U8 ku; ku.v = *reinterpret_cast<const bh8*>((char*)KW_l + ss * 512 + ((ch ^ (ss & 31)) << 4));
        const float* hp = h_l + ch * 8;
#pragma unroll
        for (int q = 0; q < 8; ++q) a += hp[q] * bf2f(ku.u[q]);
      }
      part[tid] = a;
    }
    __syncthreads();
    if (tid < 128) sc_l[tid] = (part[2 * tid] + part[2 * tid + 1] + sbreg) * 0.0625f;
    __syncthreads();
    if (tid < 64){
      float m = fmaxf(sc_l[tid], sc_l[tid + 64]);
      for (int o = 32; o; o >>= 1) m = fmaxf(m, __shfl_xor(m, o));
      if (tid == 0) red0 = m;
    }
    __syncthreads();
    if (tid < 128) sc_l[tid] = __expf(sc_l[tid] - red0);
    __syncthreads();
    if (tid < 64){
      float s = sc_l[tid] + sc_l[tid + 64];
      for (int o = 32; o; o >>= 1) s += __shfl_xor(s, o);
      if (tid == 0) red1 = s;
    }
    __syncthreads();
    if (tid < 128) at_l[tid] = sc_l[tid] / red1;
    __syncthreads();
    // gates partial
    {
      float acc = xdreg;
#pragma unroll
      for (int ci = 0; ci < 16; ++ci){
        int ch = kh * 16 + ci;
        U8 w; w.v = *reinterpret_cast<const bh8*>((char*)Ws + lr * 512 + ((ch ^ (lr & 31)) << 4));
        float4 ha = *(const float4*)(h_l + ch * 8);
        float4 hb = *(const float4*)(h_l + ch * 8 + 4);
        acc += ha.x*bf2f(w.u[0]) + ha.y*bf2f(w.u[1]) + ha.z*bf2f(w.u[2]) + ha.w*bf2f(w.u[3]);
        acc += hb.x*bf2f(w.u[4]) + hb.y*bf2f(w.u[5]) + hb.z*bf2f(w.u[6]) + hb.w*bf2f(w.u[7]);
      }
#pragma unroll
      for (int ci = 0; ci < 8; ++ci){
        const float* ap = at_l + kh * 64 + ci * 8;
#pragma unroll
        for (int q = 0; q < 8; ++q) acc += ap[q] * bf2f(vw[ci].u[q]);
      }
      part[tid] = acc;
    }
    __syncthreads();
    if (tid < 32){
      float gi = part[tid*2]      + part[tid*2 + 1];
      float gf = part[(32+tid)*2] + part[(32+tid)*2 + 1];
      float gg = part[(64+tid)*2] + part[(64+tid)*2 + 1];
      float go = part[(96+tid)*2] + part[(96+tid)*2 + 1];
      float c = sigm(gf) * creg + sigm(gi) * tanhf(gg);
      float h = sigm(go) * tanhf(c);
      creg = c;
      int j = j0 + tid;
      h_l[j] = h;
      unsigned int hb = __builtin_bit_cast(unsigned int, h);
      st_plain((unsigned int*)hbDf + (size_t)(t + 1) * 4096 + b * 256 + j, hb);
      __hip_atomic_store((unsigned int*)hbDs + (size_t)(t + 1) * 4096 + b * 256 + j, hb,
                         __ATOMIC_RELAXED, __HIP_MEMORY_SCOPE_AGENT);
      Hs[(size_t)(b * 63 + t) * 256 + j] = f2bf(h);
    }
    __syncthreads();
  }
}

// ---------------- host ----------------
extern "C" void kernel_launch(void* const* d_in, const int* in_sizes, int n_in,
                              void* d_out, int out_size, void* d_ws, size_t ws_size,
                              hipStream_t stream){
  const int expect[20] = {2048, 1024, 8192000, 262144, 262144, 1024, 8192000,
                          65536, 256, 65536, 256, 65536, 256, 65536, 256,
                          524288, 262144, 1024, 8192000, 32000};
  if (n_in != 20 || out_size != 32256000) return;
  for (int i = 0; i < 20; ++i) if (in_sizes[i] != expect[i]) return;

  const int*   input_seq  = (const int*)  d_in[0];
  const int*   target_seq = (const int*)  d_in[1];
  const float* enc_emb    = (const float*)d_in[2];
  const float* enc_Wih    = (const float*)d_in[3];
  const float* enc_Whh    = (const float*)d_in[4];
  const float* enc_b      = (const float*)d_in[5];
  const float* dec_emb    = (const float*)d_in[6];
  const float* Wq         = (const float*)d_in[7];
  const float* bq         = (const float*)d_in[8];
  const float* Wk         = (const float*)d_in[9];
  const float* bk         = (const float*)d_in[10];
  const float* Wv         = (const float*)d_in[11];
  const float* bv         = (const float*)d_in[12];
  const float* Wo         = (const float*)d_in[13];
  const float* bo         = (const float*)d_in[14];
  const float* dec_Wih    = (const float*)d_in[15];
  const float* dec_Whh    = (const float*)d_in[16];
  const float* dec_b      = (const float*)d_in[17];
  const float* Wout       = (const float*)d_in[18];
  const float* bout       = (const float*)d_in[19];

  char* p = (char*)d_ws;
  auto alloc = [&](size_t sz)->char*{ char* r = p; p += (sz + 255) & ~(size_t)255; return r; };

  // ---- zero zone ----
  unsigned short* Hs     = (unsigned short*)alloc((size_t)1024 * 256 * 2);
  size_t zsz = (size_t)(p - (char*)d_ws);
  // ---- sentinel (0xFF) zone: fast (L2) + slow (agent) mirrors, write-once ----
  float*          hbEf   = (float*)         alloc((size_t)128 * 4096 * 4);
  float*          hbEs   = (float*)         alloc((size_t)128 * 4096 * 4);
  float*          hbDf   = (float*)         alloc((size_t)64 * 4096 * 4);
  float*          hbDs   = (float*)         alloc((size_t)64 * 4096 * 4);
  size_t ffend = (size_t)(p - (char*)d_ws);
  // ---- working buffers (fully written before read) ----
  float*          cfin   = (float*)          alloc(16 * 256 * 4);
  unsigned short* src_bf  = (unsigned short*)alloc((size_t)2048 * 256 * 2);
  unsigned short* tok_bf  = (unsigned short*)alloc((size_t)1024 * 256 * 2);
  unsigned short* wih_bf  = (unsigned short*)alloc((size_t)1024 * 256 * 2);
  unsigned short* wxd_bf  = (unsigned short*)alloc((size_t)1024 * 256 * 2);
  unsigned short* wout_bf = (unsigned short*)alloc((size_t)32000 * 256 * 2);
  unsigned short* whhE_bf = (unsigned short*)alloc((size_t)1024 * 256 * 2);
  unsigned short* whhD_bf = (unsigned short*)alloc((size_t)1024 * 256 * 2);
  float*          Gf      = (float*)         alloc((size_t)1024 * 256 * 4);
  unsigned short* A3bf    = (unsigned short*)alloc((size_t)256 * 256 * 2);
  unsigned short* A2bf    = (unsigned short*)alloc((size_t)1024 * 256 * 2);
  float*          c3f     = (float*)         alloc(256 * 4);
  float*          c4f     = (float*)         alloc(256 * 4);
  float*          c5f     = (float*)         alloc(256);
  float*          xdb     = (float*)         alloc(1024 * 4);
  float*          Xg      = (float*)         alloc((size_t)2048 * 1024 * 4);
  float*          Xd      = (float*)         alloc((size_t)1024 * 1024 * 4);
  unsigned short* enc_bf  = (unsigned short*)alloc((size_t)2048 * 256 * 2);
  unsigned short* KWb     = (unsigned short*)alloc((size_t)2048 * 256 * 2);
  unsigned short* VWWT    = (unsigned short*)alloc((size_t)1024 * 2048 * 2);
  float*          sbf     = (float*)         alloc(2048 * 4);
  if ((size_t)(p - (char*)d_ws) > ws_size) return;

  hipMemsetAsync(d_ws, 0, zsz, stream);
  hipMemsetAsync((char*)d_ws + zsz, 0xFF, ffend - zsz, stream);   // sentinel fill
  hipMemsetAsync(hbEf, 0, 4096 * 4, stream);                      // h_0 = zeros (both mirrors)
  hipMemsetAsync(hbEs, 0, 4096 * 4, stream);

  // fused prep
  k_prepA<<<3591, 256, 0, stream>>>(input_seq, target_seq, enc_emb, dec_emb,
      enc_Wih, dec_Wih, Wout, enc_Whh, dec_Whh, Wq, Wk, bq, bk, Wo, bo, dec_b,
      src_bf, tok_bf, wih_bf, wxd_bf, wout_bf, whhE_bf, whhD_bf,
      Gf, A3bf, c3f, c4f, c5f, xdb);
  k_prepB<<<516, 256, 0, stream>>>(Gf, Wv, bv, A2bf, xdb);

  // fused Xg + Xd GEMMs
  k_gemmAB<<<192, 256, 0, stream>>>(src_bf, wih_bf, enc_b, Xg, tok_bf, wxd_bf, xdb, Xd);

  // encoder: dual-path sentinel dataflow (plain-store fast lane)
  k_enc_g<<<128, 256, 0, stream>>>(whhE_bf, Xg, enc_bf, hbEf, hbEs, hbDf, hbDs, cfin);

  // fused post-encoder: KW + VWWT + sb
  k_gemmPost<<<168, 256, 0, stream>>>(enc_bf, A3bf, c3f, KWb, A2bf, VWWT, c4f, c5f, sbf);

  // decoder: one-hop dual-path sentinel dataflow
  k_dec_g<<<128, 256, 0, stream>>>(whhD_bf, Xd, KWb, VWWT, sbf, hbDf, hbDs, cfin, Hs);

  // logits -> FP32 d_out
  k_gemm<<<dim3(250, 8), 256, 0, stream>>>(Hs, wout_bf, bout, (float*)d_out, nullptr, 1008, 32000);
}